// Round 5
// baseline (508.146 us; speedup 1.0000x reference)
//
#include <hip/hip_runtime.h>

#define B_ 32
#define T_ 2048
#define D_ 512
// 1024 blocks = 32 batches x 32 chunks of 64 rows. 4 blocks/CU (co-resident).

__global__ __launch_bounds__(256) void fused_attn_kernel(
    const float* __restrict__ q,
    const float* __restrict__ key,
    const float* __restrict__ value,
    float* __restrict__ out,        // [B, D]
    float* __restrict__ attn,       // [B, T]
    int*   __restrict__ cnt,        // [2*B] zeroed counters
    float* __restrict__ stats,      // ws [B, 32, 2]
    float* __restrict__ partial)    // ws [B, 32, D]
{
    const int b    = blockIdx.x >> 5;
    const int sub  = blockIdx.x & 31;
    const int t0   = sub * 64;
    const int tid  = threadIdx.x;
    const int wave = tid >> 6;
    const int lane = tid & 63;

    __shared__ float  es[64];       // this block's 64 energies
    __shared__ float  asx[64];      // this block's 64 attention weights
    __shared__ float  MS[2];
    __shared__ float4 red4[128];
    __shared__ int    isLast;

    // ---------------- P1: energies for rows t0..t0+63 ----------------
    {
        const float4 qv0 = ((const float4*)q)[b * 128 + lane];
        const float4 qv1 = ((const float4*)q)[b * 128 + 64 + lane];
        const int tr = t0 + wave * 16;                    // 16 rows per wave
        const float4* kbase = (const float4*)key + ((size_t)b * T_ + tr) * 128;
#pragma unroll 4
        for (int r = 0; r < 16; ++r) {
            const float4 k0 = kbase[r * 128 + lane];
            const float4 k1 = kbase[r * 128 + 64 + lane];
            float acc = k0.x * qv0.x + k0.y * qv0.y + k0.z * qv0.z + k0.w * qv0.w
                      + k1.x * qv1.x + k1.y * qv1.y + k1.z * qv1.z + k1.w * qv1.w;
#pragma unroll
            for (int off = 32; off >= 1; off >>= 1)
                acc += __shfl_down(acc, off);
            if (lane == 0)
                es[wave * 16 + r] = acc;
        }
    }
    __syncthreads();

    // ---- per-chunk stats over the 64 energies (wave 0) ----
    if (tid < 64) {
        const float e = es[tid];
        float m = e;
#pragma unroll
        for (int off = 32; off >= 1; off >>= 1)
            m = fmaxf(m, __shfl_xor(m, off));
        float s = __expf(e - m);
#pragma unroll
        for (int off = 32; off >= 1; off >>= 1)
            s += __shfl_xor(s, off);
        if (tid == 0) {
            stats[((size_t)b * 32 + sub) * 2 + 0] = m;
            stats[((size_t)b * 32 + sub) * 2 + 1] = s;
            __threadfence();                       // publish stats (device scope)
            atomicAdd(&cnt[b], 1);
        }
    }

    // ---------------- wait: all 32 chunks of batch b done ----------------
    if (tid == 0) {
        int it = 0;
        while (__hip_atomic_load(&cnt[b], __ATOMIC_ACQUIRE,
                                 __HIP_MEMORY_SCOPE_AGENT) < 32) {
            __builtin_amdgcn_s_sleep(2);
            if (++it > (1 << 20)) break;           // loud-fail, never hang
        }
        __threadfence();
    }
    __syncthreads();

    // ---- combine the batch's 32 chunk stats (lanes 0..31) ----
    if (tid < 32) {
        const float m_c = stats[((size_t)b * 32 + tid) * 2 + 0];
        const float s_c = stats[((size_t)b * 32 + tid) * 2 + 1];
        float M = m_c;
#pragma unroll
        for (int off = 16; off >= 1; off >>= 1)
            M = fmaxf(M, __shfl_xor(M, off));
        float S = s_c * __expf(m_c - M);
#pragma unroll
        for (int off = 16; off >= 1; off >>= 1)
            S += __shfl_xor(S, off);
        if (tid == 0) { MS[0] = M; MS[1] = S; }
    }
    __syncthreads();
    const float M    = MS[0];
    const float invS = 1.f / MS[1];

    // ---- attention weights for this chunk (energies still in LDS) ----
    if (tid < 64) {
        const float a = __expf(es[tid] - M) * invS;
        asx[tid] = a;
        attn[b * T_ + t0 + tid] = a;
    }
    __syncthreads();

    // ---------------- P2: context partial over value ----------------
    const int tg = tid >> 7;            // row group 0..1
    const int d4 = tid & 127;           // float4 slice of D
    {
        const float4* v4 = (const float4*)value + ((size_t)b * T_ + t0 + tg) * 128 + d4;
        float4 acc = {0.f, 0.f, 0.f, 0.f};
#pragma unroll 8
        for (int i = 0; i < 32; ++i) {  // t = t0 + 2*i + tg
            const float a = asx[2 * i + tg];
            const float4 vv = v4[i * 256];
            acc.x += a * vv.x; acc.y += a * vv.y;
            acc.z += a * vv.z; acc.w += a * vv.w;
        }
        if (tg == 1) red4[d4] = acc;
        __syncthreads();
        if (tg == 0) {
            const float4 o = red4[d4];
            acc.x += o.x; acc.y += o.y; acc.z += o.z; acc.w += o.w;
            ((float4*)partial)[((size_t)b * 32 + sub) * 128 + d4] = acc;
        }
    }

    // ---------------- P3: last block of batch b reduces partials ----------------
    if (tid == 0) __threadfence();      // publish partial (all lanes' stores
    __syncthreads();                    // ordered via barrier before fence+RMW)
    if (tid == 0) {
        __threadfence();
        const int old = atomicAdd(&cnt[B_ + b], 1);
        isLast = (old == 31);
        if (isLast) __threadfence();    // acquire side
    }
    __syncthreads();
    if (isLast && tid < 128) {
        float4 s = {0.f, 0.f, 0.f, 0.f};
#pragma unroll
        for (int c = 0; c < 32; ++c) {
            const float4 p = ((const float4*)partial)[((size_t)b * 32 + c) * 128 + tid];
            s.x += p.x; s.y += p.y; s.z += p.z; s.w += p.w;
        }
        ((float4*)out)[b * 128 + tid] = s;
    }
}

extern "C" void kernel_launch(void* const* d_in, const int* in_sizes, int n_in,
                              void* d_out, int out_size, void* d_ws, size_t ws_size,
                              hipStream_t stream)
{
    const float* q     = (const float*)d_in[0];   // [B, D]
    const float* key   = (const float*)d_in[1];   // [B, T, D]
    const float* value = (const float*)d_in[2];   // [B, T, D]

    float* out  = (float*)d_out;                  // [B, D] first
    float* attn = out + B_ * D_;                  // [B, T] second

    int*   cnt     = (int*)d_ws;                  // [2*B] counters
    float* stats   = (float*)d_ws + 2 * B_;       // [B*32*2]
    float* partial = stats + B_ * 32 * 2;         // [B*32*D] (2 MiB)

    hipMemsetAsync(cnt, 0, 2 * B_ * sizeof(int), stream);
    fused_attn_kernel<<<B_ * 32, 256, 0, stream>>>(
        q, key, value, out, attn, cnt, stats, partial);
}

// Round 6
// 284.848 us; speedup vs baseline: 1.7839x; 1.7839x over previous
//
#include <hip/hip_runtime.h>

#define B_ 32
#define T_ 2048
#define D_ 512

// ---------------- Kernel A: per (b, 32-row chunk) -------------------------
// energies -> local stats (m_c, s_c) -> a_loc = exp(e - m_c) ->
// unnormalized context partial P_c = sum_t a_loc[t] * value[t,:].
// 2048 blocks x 256 threads (8 blocks/CU). No cross-block dependencies.
__global__ __launch_bounds__(256) void chunk_kernel(
    const float* __restrict__ q,
    const float* __restrict__ key,
    const float* __restrict__ value,
    float* __restrict__ a_loc,      // ws [B, T]
    float* __restrict__ stats,      // ws [B, 64, 2]
    float* __restrict__ partial)    // ws [B, 64, D]
{
    const int b    = blockIdx.x >> 6;
    const int sub  = blockIdx.x & 63;
    const int t0   = sub * 32;
    const int tid  = threadIdx.x;
    const int wave = tid >> 6;
    const int lane = tid & 63;

    __shared__ float  es[32];       // chunk energies
    __shared__ float  asx[32];      // exp(e - m_c)
    __shared__ float4 red4[128];

    // ---- P1: energies, 4 waves x 8 rows ----
    {
        const float4 qv0 = ((const float4*)q)[b * 128 + lane];
        const float4 qv1 = ((const float4*)q)[b * 128 + 64 + lane];
        const int tr = t0 + wave * 8;
        const float4* kbase = (const float4*)key + ((size_t)b * T_ + tr) * 128;
#pragma unroll
        for (int r = 0; r < 8; ++r) {
            const float4 k0 = kbase[r * 128 + lane];
            const float4 k1 = kbase[r * 128 + 64 + lane];
            float acc = k0.x * qv0.x + k0.y * qv0.y + k0.z * qv0.z + k0.w * qv0.w
                      + k1.x * qv1.x + k1.y * qv1.y + k1.z * qv1.z + k1.w * qv1.w;
#pragma unroll
            for (int off = 32; off >= 1; off >>= 1)
                acc += __shfl_down(acc, off);
            if (lane == 0)
                es[wave * 8 + r] = acc;
        }
    }
    __syncthreads();

    // ---- P2: local stats + unnormalized attention (lanes 0..31 of wave 0) ----
    if (tid < 32) {
        const float e = es[tid];
        float m = e;
#pragma unroll
        for (int off = 16; off >= 1; off >>= 1)
            m = fmaxf(m, __shfl_xor(m, off));
        const float a = __expf(e - m);
        float s = a;
#pragma unroll
        for (int off = 16; off >= 1; off >>= 1)
            s += __shfl_xor(s, off);
        asx[tid] = a;
        a_loc[b * T_ + t0 + tid] = a;
        if (tid == 0) {
            stats[((size_t)b * 64 + sub) * 2 + 0] = m;
            stats[((size_t)b * 64 + sub) * 2 + 1] = s;
        }
    }
    __syncthreads();

    // ---- P3: unnormalized context partial (2 row-groups x 128 d4-slices) ----
    const int tg = tid >> 7;
    const int d4 = tid & 127;
    const float4* v4 = (const float4*)value + ((size_t)b * T_ + t0 + tg) * 128 + d4;
    float4 acc = {0.f, 0.f, 0.f, 0.f};
#pragma unroll
    for (int i = 0; i < 16; ++i) {      // t = t0 + 2*i + tg
        const float a = asx[2 * i + tg];
        const float4 vv = v4[i * 256];
        acc.x += a * vv.x; acc.y += a * vv.y;
        acc.z += a * vv.z; acc.w += a * vv.w;
    }
    if (tg == 1) red4[d4] = acc;
    __syncthreads();
    if (tg == 0) {
        const float4 o = red4[d4];
        acc.x += o.x; acc.y += o.y; acc.z += o.z; acc.w += o.w;
        ((float4*)partial)[((size_t)b * 64 + sub) * 128 + d4] = acc;
    }
}

// ---------------- Kernel B: combine + finalize ----------------------------
// 64 blocks = (b, half). Combine 64 chunk stats -> w_c = exp(m_c - M)/S;
// attn = a_loc * w_c (1024 rows per half); out = sum_c w_c * P_c (64 d4/half).
__global__ __launch_bounds__(256) void finalize_kernel(
    const float* __restrict__ a_loc,
    const float* __restrict__ stats,
    const float* __restrict__ partial,
    float* __restrict__ out,        // [B, D]
    float* __restrict__ attn)       // [B, T]
{
    const int b    = blockIdx.x >> 1;
    const int h    = blockIdx.x & 1;
    const int tid  = threadIdx.x;
    const int lane = tid & 63;
    const int qd   = tid >> 6;

    __shared__ float  wc[64];
    __shared__ float4 redo[256];

    // ---- combine the batch's 64 chunk stats (wave 0) ----
    if (tid < 64) {
        const float m_c = stats[((size_t)b * 64 + tid) * 2 + 0];
        const float s_c = stats[((size_t)b * 64 + tid) * 2 + 1];
        float M = m_c;
#pragma unroll
        for (int off = 32; off >= 1; off >>= 1)
            M = fmaxf(M, __shfl_xor(M, off));
        float S = s_c * __expf(m_c - M);
#pragma unroll
        for (int off = 32; off >= 1; off >>= 1)
            S += __shfl_xor(S, off);
        wc[tid] = __expf(m_c - M) / S;
    }
    __syncthreads();

    // ---- attn rows [h*1024, h*1024+1024), 4 per thread ----
    {
        const int t = h * 1024 + tid * 4;
        const float w = wc[t >> 5];
        float4 a = ((const float4*)(a_loc + (size_t)b * T_))[h * 256 + tid];
        a.x *= w; a.y *= w; a.z *= w; a.w *= w;
        ((float4*)(attn + (size_t)b * T_))[h * 256 + tid] = a;
    }

    // ---- out: slice d4 = h*64 + lane; chunk subset 16 per qd-group ----
    {
        const int d4 = h * 64 + lane;
        float4 acc = {0.f, 0.f, 0.f, 0.f};
#pragma unroll
        for (int i = 0; i < 16; ++i) {
            const int c = qd * 16 + i;
            const float w = wc[c];
            const float4 p = ((const float4*)partial)[((size_t)b * 64 + c) * 128 + d4];
            acc.x += w * p.x; acc.y += w * p.y;
            acc.z += w * p.z; acc.w += w * p.w;
        }
        redo[tid] = acc;
        __syncthreads();
        if (qd == 0) {
            const float4 a1 = redo[64 + lane];
            const float4 a2 = redo[128 + lane];
            const float4 a3 = redo[192 + lane];
            acc.x += a1.x + a2.x + a3.x;
            acc.y += a1.y + a2.y + a3.y;
            acc.z += a1.z + a2.z + a3.z;
            acc.w += a1.w + a2.w + a3.w;
            ((float4*)out)[b * 128 + d4] = acc;
        }
    }
}

extern "C" void kernel_launch(void* const* d_in, const int* in_sizes, int n_in,
                              void* d_out, int out_size, void* d_ws, size_t ws_size,
                              hipStream_t stream)
{
    const float* q     = (const float*)d_in[0];   // [B, D]
    const float* key   = (const float*)d_in[1];   // [B, T, D]
    const float* value = (const float*)d_in[2];   // [B, T, D]

    float* out  = (float*)d_out;                  // [B, D] first
    float* attn = out + B_ * D_;                  // [B, T] second

    float* a_loc   = (float*)d_ws;                // B*T        (256 KiB)
    float* stats   = a_loc + (size_t)B_ * T_;     // B*64*2     (16 KiB)
    float* partial = stats + (size_t)B_ * 64 * 2; // B*64*D     (4 MiB)

    chunk_kernel<<<B_ * 64, 256, 0, stream>>>(q, key, value, a_loc, stats, partial);
    finalize_kernel<<<B_ * 2, 256, 0, stream>>>(a_loc, stats, partial, out, attn);
}